// Round 1
// baseline (938.197 us; speedup 1.0000x reference)
//
#include <hip/hip_runtime.h>

#define Bq   16
#define Sq   512
#define Vq   128
#define NCq  10000
#define G3q  384   // 3V

// ---- workspace layout (float offsets) ----
#define OFF_XP     0u          // [8192][384]  pure dot(v_d, W_ih[:, :V].T)
#define OFF_PRE1   3145728u    // [8192][128]  pure dot(v_d, m2_W1[V:2V, :])
#define OFF_WTIH   4194304u    // [128][384]   W_ih[:, :V] transposed
#define OFF_WHHT   4243456u    // [128][384]   W_hh transposed
#define OFF_WVRIH  4292608u    // [384]  v_r @ W_ih[:, V:2V].T
#define OFF_WVR1   4292992u    // [128]  v_r @ m2_W1[2V:3V, :]
#define OFF_WVB    4293120u    // [128]  v_beta @ m2_W1[0:V, :]
#define OFF_FO     4293248u    // int [16][10000] first occurrence (S if none)
#define OFF_NO     4453248u    // int [16][512]   next occurrence (S if none)
#define OFF_PO     4461440u    // int [16][512]   prev occurrence (-1 if none)
// total 4469632 floats = 17.9 MB

// ============ K0: transposes, small vectors, occurrence tables, gamma ============
__global__ __launch_bounds__(256) void k0_prep(
    const int* __restrict__ c_seq, const int* __restrict__ d_seq,
    const float* __restrict__ D1_w,
    const float* __restrict__ W_ih, const float* __restrict__ W_hh,
    const float* __restrict__ v_r, const float* __restrict__ v_beta,
    const float* __restrict__ m2W1,
    float* __restrict__ ws, float* __restrict__ gamma_out)
{
    const int blk = blockIdx.x, tid = threadIdx.x;
    float* WTIH = ws + OFF_WTIH;
    float* WHHT = ws + OFF_WHHT;

    if (blk < 128) {
        // transpose W_ih[:, :128] -> WTIH[k][g], and W_hh -> WHHT[k][g]
        int base = blk * 768;
        for (int i = tid; i < 768; i += 256) {
            int e = base + i;
            if (e < 49152) { int k = e / 384, g = e % 384; WTIH[e] = W_ih[g * 256 + k]; }
            else { int e2 = e - 49152; int k = e2 / 384, g = e2 % 384; WHHT[e2] = W_hh[g * 128 + k]; }
        }
    } else if (blk == 128) {
        float* WVRIH = ws + OFF_WVRIH;
        float* WVR1  = ws + OFF_WVR1;
        float* WVB   = ws + OFF_WVB;
        for (int g = tid; g < 384; g += 256) {
            float a = 0.f;
            for (int k = 0; k < 128; ++k) a = fmaf(v_r[k], W_ih[g * 256 + 128 + k], a);
            WVRIH[g] = a;
        }
        if (tid < 128) {
            float a = 0.f, b = 0.f;
            for (int k = 0; k < 128; ++k) {
                a = fmaf(v_r[k],    m2W1[(256 + k) * 128 + tid], a);
                b = fmaf(v_beta[k], m2W1[k * 128 + tid],         b);
            }
            WVR1[tid] = a; WVB[tid] = b;
        }
    } else if (blk < 145) {
        // per-batch occurrence tables
        const int b = blk - 129;
        __shared__ int cs[Sq];
        for (int i = tid; i < Sq; i += 256) cs[i] = c_seq[b * Sq + i];
        int* FO = (int*)(ws + OFF_FO) + b * NCq;
        for (int c = tid; c < NCq; c += 256) FO[c] = Sq;
        __syncthreads();
        for (int t = tid; t < Sq; t += 256) atomicMin(&FO[cs[t]], t);
        int* NO = (int*)(ws + OFF_NO) + b * Sq;
        int* PO = (int*)(ws + OFF_PO) + b * Sq;
        for (int t = tid; t < Sq; t += 256) {
            int c = cs[t];
            int no = Sq;
            for (int u = t + 1; u < Sq; ++u) if (cs[u] == c) { no = u; break; }
            NO[t] = no;
            int po = -1;
            for (int u = t - 1; u >= 0; --u) if (cs[u] == c) { po = u; break; }
            PO[t] = po;
        }
    } else if (blk < 161) {
        const int b = blk - 145;
        for (int s = tid; s < Sq; s += 256)
            gamma_out[b * Sq + s] = D1_w[d_seq[b * Sq + s]];
    }
}

// ============ K1: batched GEMM  [8192,128] x [128,512] -> xp | pre1 ============
// grid = 128 row-tiles x 8 col-tiles (cols 0..383 -> xp, 384..511 -> pre1)
__global__ __launch_bounds__(256) void k1_gemm(
    const int* __restrict__ d_seq, const float* __restrict__ D2_w,
    const float* __restrict__ m2W1, float* __restrict__ ws)
{
    __shared__ float As[64 * 128];   // [r][k]
    __shared__ float Bs[128 * 64];   // [k][c]
    const int blk = blockIdx.x, tid = threadIdx.x;
    const int nc = blk & 7;
    const int m0 = (blk >> 3) * 64;
    const float* WTIH = ws + OFF_WTIH;

    const float4* D2v = (const float4*)D2_w;
    for (int e = tid; e < 2048; e += 256) {          // A: 64 rows x 32 float4
        int r = e >> 5, q = e & 31;
        int d = d_seq[m0 + r];
        *(float4*)&As[r * 128 + 4 * q] = D2v[d * 32 + q];
    }
    for (int e = tid; e < 2048; e += 256) {          // B: 128 k x 16 float4
        int k = e >> 4, q = e & 15;
        float4 v;
        if (nc < 6) v = *(const float4*)&WTIH[k * 384 + nc * 64 + 4 * q];
        else        v = *(const float4*)&m2W1[(128 + k) * 128 + (nc - 6) * 64 + 4 * q];
        *(float4*)&Bs[k * 64 + 4 * q] = v;
    }
    __syncthreads();

    const int tx = tid & 15, ty = tid >> 4;
    const int c0 = 4 * tx, r0 = 4 * ty;
    float acc[4][4];
#pragma unroll
    for (int i = 0; i < 4; ++i)
#pragma unroll
        for (int j = 0; j < 4; ++j) acc[i][j] = 0.f;

    for (int k = 0; k < 128; ++k) {
        float4 bv = *(const float4*)&Bs[k * 64 + c0];
#pragma unroll
        for (int i = 0; i < 4; ++i) {
            float a = As[(r0 + i) * 128 + k];
            acc[i][0] = fmaf(a, bv.x, acc[i][0]);
            acc[i][1] = fmaf(a, bv.y, acc[i][1]);
            acc[i][2] = fmaf(a, bv.z, acc[i][2]);
            acc[i][3] = fmaf(a, bv.w, acc[i][3]);
        }
    }
    float* XP   = ws + OFF_XP;
    float* PRE1 = ws + OFF_PRE1;
#pragma unroll
    for (int i = 0; i < 4; ++i) {
        int row = m0 + r0 + i;
        float4 v = make_float4(acc[i][0], acc[i][1], acc[i][2], acc[i][3]);
        if (nc < 6) *(float4*)&XP[row * 384 + nc * 64 + c0] = v;
        else        *(float4*)&PRE1[row * 128 + (nc - 6) * 64 + c0] = v;
    }
}

// ============ K2: GRU scan (blk 0..15) | beta scan + spans (16..31) | C zeros (32..255) ============
__global__ __launch_bounds__(384) void k2_scan(
    const int* __restrict__ c_seq, const float* __restrict__ r_seq,
    const float* __restrict__ b_ih, const float* __restrict__ b_hh,
    const float* __restrict__ m2W2, const float* __restrict__ m2b1,
    const float* __restrict__ m2b2, const float* __restrict__ m2W3,
    const float* __restrict__ m2b3,
    float* __restrict__ ws,
    float* __restrict__ hseq_out, float* __restrict__ beta_out,
    float* __restrict__ C_out)
{
    __shared__ union {
        struct { float h[128]; float sum[256]; float xn[128]; float hn[128]; float r[512]; } g;
        struct { float bh[512]; float h1[128]; float red[2]; float r2[512];
                 int cs[512]; int no[512]; int po[512]; } bt;
    } sm;

    const int blk = blockIdx.x, tid = threadIdx.x;

    if (blk < 16) {
        // ---------------- GRU scan, batch b ----------------
        const int b = blk;
        const float* WHHT = ws + OFF_WHHT;
        float w[128];
#pragma unroll
        for (int k = 0; k < 128; ++k) w[k] = WHHT[k * 384 + tid];
        const float wvr = (ws + OFF_WVRIH)[tid];
        const float bih = b_ih[tid];
        const float bhh = b_hh[tid];
        for (int i = tid; i < Sq; i += 384) sm.g.r[i] = r_seq[b * Sq + i];
        if (tid < 128) sm.g.h[tid] = 0.f;
        __syncthreads();

        const float* xpb = ws + OFF_XP + (size_t)b * Sq * 384;
        float xp0 = xpb[tid];
        float xp1 = xpb[384 + tid];
        const float4* h4 = (const float4*)sm.g.h;

        for (int t = 0; t < Sq; ++t) {
            float xp2 = (t < Sq - 2) ? xpb[(t + 2) * 384 + tid] : 0.f;
            float x = xp0 + sm.g.r[t] * wvr + bih;
            float a0 = 0.f, a1 = 0.f, a2 = 0.f, a3 = 0.f;
#pragma unroll
            for (int kk = 0; kk < 32; ++kk) {
                float4 hv = h4[kk];
                a0 = fmaf(w[4 * kk + 0], hv.x, a0);
                a1 = fmaf(w[4 * kk + 1], hv.y, a1);
                a2 = fmaf(w[4 * kk + 2], hv.z, a2);
                a3 = fmaf(w[4 * kk + 3], hv.w, a3);
            }
            float hp = (a0 + a1) + (a2 + a3) + bhh;
            if (tid < 256) sm.g.sum[tid] = x + hp;
            else { sm.g.xn[tid - 256] = x; sm.g.hn[tid - 256] = hp; }
            __syncthreads();
            if (tid < 128) {
                float r = 1.f / (1.f + __expf(-sm.g.sum[tid]));
                float z = 1.f / (1.f + __expf(-sm.g.sum[128 + tid]));
                float npre = sm.g.xn[tid] + r * sm.g.hn[tid];
                float ax = fabsf(npre);
                float e2 = __expf(-2.f * ax);
                float n = copysignf((1.f - e2) / (1.f + e2), npre);
                float hnew = (1.f - z) * n + z * sm.g.h[tid];
                sm.g.h[tid] = hnew;
                hseq_out[(size_t)(b * Sq + t) * 128 + tid] = hnew;
            }
            __syncthreads();
            xp0 = xp1; xp1 = xp2;
        }
    } else if (blk < 32) {
        // ---------------- beta scan + C spans, batch b ----------------
        const int b = blk - 16;
        float w2[128];
        float wvbj = 0.f, wvr1j = 0.f, b1j = 0.f, b2j = 0.f, w3j = 0.f;
        if (tid < 128) {
#pragma unroll
            for (int k = 0; k < 128; ++k) w2[k] = m2W2[k * 128 + tid];
            wvbj  = (ws + OFF_WVB)[tid];
            wvr1j = (ws + OFF_WVR1)[tid];
            b1j = m2b1[tid]; b2j = m2b2[tid]; w3j = m2W3[tid];
        }
        const float b3v = m2b3[0];
        const int* NO = (const int*)(ws + OFF_NO) + b * Sq;
        const int* PO = (const int*)(ws + OFF_PO) + b * Sq;
        for (int i = tid; i < Sq; i += 384) {
            sm.bt.r2[i] = r_seq[b * Sq + i];
            sm.bt.cs[i] = c_seq[b * Sq + i];
            sm.bt.no[i] = NO[i];
            sm.bt.po[i] = PO[i];
        }
        __syncthreads();

        const float* p1b = ws + OFF_PRE1 + (size_t)b * Sq * 128;
        float p1 = (tid < 128) ? p1b[tid] : 0.f;
        const float4* h14 = (const float4*)sm.bt.h1;
        float* Cb = C_out + (size_t)b * Sq * NCq;

        for (int t = 0; t < Sq; ++t) {
            float p1n = (tid < 128 && t < Sq - 1) ? p1b[(t + 1) * 128 + tid] : 0.f;
            if (tid < 128) {
                int po = sm.bt.po[t];
                float bp = (po >= 0) ? sm.bt.bh[po] : 0.f;
                float h1 = fmaxf(0.f, fmaf(bp, wvbj, p1 + sm.bt.r2[t] * wvr1j + b1j));
                sm.bt.h1[tid] = h1;
            }
            __syncthreads();
            if (tid < 128) {
                float a0 = 0.f, a1 = 0.f, a2 = 0.f, a3 = 0.f;
#pragma unroll
                for (int kk = 0; kk < 32; ++kk) {
                    float4 hv = h14[kk];
                    a0 = fmaf(w2[4 * kk + 0], hv.x, a0);
                    a1 = fmaf(w2[4 * kk + 1], hv.y, a1);
                    a2 = fmaf(w2[4 * kk + 2], hv.z, a2);
                    a3 = fmaf(w2[4 * kk + 3], hv.w, a3);
                }
                float h2 = fmaxf(0.f, (a0 + a1) + (a2 + a3) + b2j);
                float part = h2 * w3j;
#pragma unroll
                for (int off = 1; off < 64; off <<= 1) part += __shfl_xor(part, off);
                if ((tid & 63) == 0) sm.bt.red[tid >> 6] = part;
            }
            __syncthreads();
            if (tid == 0) {
                float bta = sm.bt.red[0] + sm.bt.red[1] + b3v;
                sm.bt.bh[t] = bta;
                beta_out[b * Sq + t] = bta;
            }
            __syncthreads();
            {
                float bta = sm.bt.bh[t];
                int ct = sm.bt.cs[t];
                int no = sm.bt.no[t];
                for (int tp = t + tid; tp < no; tp += 384)
                    Cb[(size_t)tp * NCq + ct] = bta;
            }
            p1 = p1n;
        }
    } else {
        // ---------------- zero writer: C[b, t', c] = 0 for t' < fo[b][c] ----------------
        const int z = blk - 32;             // 0..223
        const int b = z / 14;
        const int piece = z % 14;
        const int chunk = piece >> 1;       // 0..6, 1536 cols each
        const int th = piece & 1;           // t-half
        const int tlo = th ? 256 : 0;
        const int thi = th ? 512 : 256;
        const int c0 = chunk * 1536 + tid * 4;
        const int* FO = (const int*)(ws + OFF_FO) + b * NCq;
        int f[4];
#pragma unroll
        for (int i = 0; i < 4; ++i) {
            int c = c0 + i;
            f[i] = (c < NCq) ? FO[c] : 0;
        }
        int m = min(min(f[0], f[1]), min(f[2], f[3]));
        float* base = C_out + (size_t)b * Sq * NCq;
        const float4 z4 = make_float4(0.f, 0.f, 0.f, 0.f);
        int e1 = min(m, thi);
        for (int tp = tlo; tp < e1; ++tp)
            *(float4*)&base[(size_t)tp * NCq + c0] = z4;
#pragma unroll
        for (int i = 0; i < 4; ++i) {
            int e = min(f[i], thi);
            for (int tp = max(m, tlo); tp < e; ++tp)
                base[(size_t)tp * NCq + c0 + i] = 0.f;
        }
    }
}

// ============ K3: alpha = mlp1(h_seq) ============
__global__ __launch_bounds__(256) void k3_alpha(
    const float* __restrict__ hseq,
    const float* __restrict__ W1, const float* __restrict__ b1,
    const float* __restrict__ W2, const float* __restrict__ b2,
    const float* __restrict__ W3, const float* __restrict__ b3,
    float* __restrict__ alpha_out)
{
    __shared__ float Hs[32 * 128];
    __shared__ float T1[32 * 128];
    __shared__ float red[4][16];
    const int blk = blockIdx.x, tid = threadIdx.x;
    const int row0 = blk * 32;

    for (int e = tid; e < 1024; e += 256) {
        int r = e >> 5, q = e & 31;
        *(float4*)&Hs[r * 128 + 4 * q] =
            *(const float4*)&hseq[(size_t)(row0 + r) * 128 + 4 * q];
    }
    __syncthreads();

    const int j = tid & 127, rh = tid >> 7;
    const float b1j = b1[j], b2j = b2[j], w3j = W3[j];
    float acc[16];
#pragma unroll
    for (int r = 0; r < 16; ++r) acc[r] = b1j;
    for (int k = 0; k < 128; ++k) {
        float w = W1[k * 128 + j];
#pragma unroll
        for (int r = 0; r < 16; ++r)
            acc[r] = fmaf(Hs[(rh * 16 + r) * 128 + k], w, acc[r]);
    }
#pragma unroll
    for (int r = 0; r < 16; ++r) {
        acc[r] = fmaxf(acc[r], 0.f);
        T1[(rh * 16 + r) * 128 + j] = acc[r];
    }
    __syncthreads();
    float acc2[16];
#pragma unroll
    for (int r = 0; r < 16; ++r) acc2[r] = b2j;
    for (int k = 0; k < 128; ++k) {
        float w = W2[k * 128 + j];
#pragma unroll
        for (int r = 0; r < 16; ++r)
            acc2[r] = fmaf(T1[(rh * 16 + r) * 128 + k], w, acc2[r]);
    }
#pragma unroll
    for (int r = 0; r < 16; ++r) {
        float p = fmaxf(acc2[r], 0.f) * w3j;
#pragma unroll
        for (int off = 1; off < 64; off <<= 1) p += __shfl_xor(p, off);
        if ((tid & 63) == 0) red[tid >> 6][r] = p;
    }
    __syncthreads();
    if (tid < 32) {
        int rr = tid & 15, g = tid >> 4;
        alpha_out[row0 + g * 16 + rr] = red[2 * g][rr] + red[2 * g + 1][rr] + b3[0];
    }
}

extern "C" void kernel_launch(void* const* d_in, const int* in_sizes, int n_in,
                              void* d_out, int out_size, void* d_ws, size_t ws_size,
                              hipStream_t stream) {
    const int*   c_seq = (const int*)d_in[0];
    const int*   d_seq = (const int*)d_in[1];
    const float* r_seq = (const float*)d_in[2];
    const float* D1_w  = (const float*)d_in[3];
    const float* D2_w  = (const float*)d_in[4];
    const float* v_r   = (const float*)d_in[5];
    const float* v_b   = (const float*)d_in[6];
    const float* W_ih  = (const float*)d_in[7];
    const float* W_hh  = (const float*)d_in[8];
    const float* b_ih  = (const float*)d_in[9];
    const float* b_hh  = (const float*)d_in[10];
    const float* m1W1  = (const float*)d_in[11];
    const float* m1b1  = (const float*)d_in[12];
    const float* m1W2  = (const float*)d_in[13];
    const float* m1b2  = (const float*)d_in[14];
    const float* m1W3  = (const float*)d_in[15];
    const float* m1b3  = (const float*)d_in[16];
    const float* m2W1  = (const float*)d_in[17];
    const float* m2b1  = (const float*)d_in[18];
    const float* m2W2  = (const float*)d_in[19];
    const float* m2b2  = (const float*)d_in[20];
    const float* m2W3  = (const float*)d_in[21];
    const float* m2b3  = (const float*)d_in[22];

    float* out   = (float*)d_out;
    float* alpha = out;                 // [16*512]
    float* beta  = out + 8192;          // [16*512]
    float* gamma = out + 16384;         // [16*512]
    float* hseq  = out + 24576;         // [16*512*128]
    float* Cseq  = out + 1073152;       // [16*512*10000]
    float* ws    = (float*)d_ws;

    hipLaunchKernelGGL(k0_prep, dim3(161), dim3(256), 0, stream,
                       c_seq, d_seq, D1_w, W_ih, W_hh, v_r, v_b, m2W1, ws, gamma);
    hipLaunchKernelGGL(k1_gemm, dim3(1024), dim3(256), 0, stream,
                       d_seq, D2_w, m2W1, ws);
    hipLaunchKernelGGL(k2_scan, dim3(256), dim3(384), 0, stream,
                       c_seq, r_seq, b_ih, b_hh, m2W2, m2b1, m2b2, m2W3, m2b3,
                       ws, hseq, beta, Cseq);
    hipLaunchKernelGGL(k3_alpha, dim3(256), dim3(256), 0, stream,
                       hseq, m1W1, m1b1, m1W2, m1b2, m1W3, m1b3, alpha);
}

// Round 2
// 721.840 us; speedup vs baseline: 1.2997x; 1.2997x over previous
//
#include <hip/hip_runtime.h>

#define Bq   16
#define Sq   512
#define Vq   128
#define NCq  10000

// ---- workspace layout (float offsets) ----
#define OFF_XP     0u          // [8192][384]  pure dot(v_d, W_ih[:, :V].T)
#define OFF_PRE1   3145728u    // [8192][128]  pure dot(v_d, m2_W1[V:2V, :])
#define OFF_WTIH   4194304u    // [128][384]   W_ih[:, :V] transposed
#define OFF_WHHT   4243456u    // [128][384]   W_hh transposed
#define OFF_WVRIH  4292608u    // [384]  v_r @ W_ih[:, V:2V].T
#define OFF_WVR1   4292992u    // [128]  v_r @ m2_W1[2V:3V, :]
#define OFF_WVB    4293120u    // [128]  v_beta @ m2_W1[0:V, :]
#define OFF_PO     4293248u    // int [16][512]   prev occurrence (-1 if none)
// total 4301440 floats = 17.2 MB

// ============ K0: transposes, small vectors, prev-occurrence, gamma ============
__global__ __launch_bounds__(256) void k0_prep(
    const int* __restrict__ c_seq, const int* __restrict__ d_seq,
    const float* __restrict__ D1_w,
    const float* __restrict__ W_ih, const float* __restrict__ W_hh,
    const float* __restrict__ v_r, const float* __restrict__ v_beta,
    const float* __restrict__ m2W1,
    float* __restrict__ ws, float* __restrict__ gamma_out)
{
    const int blk = blockIdx.x, tid = threadIdx.x;
    float* WTIH = ws + OFF_WTIH;
    float* WHHT = ws + OFF_WHHT;

    if (blk < 128) {
        int base = blk * 768;
        for (int i = tid; i < 768; i += 256) {
            int e = base + i;
            if (e < 49152) { int k = e / 384, g = e % 384; WTIH[e] = W_ih[g * 256 + k]; }
            else { int e2 = e - 49152; int k = e2 / 384, g = e2 % 384; WHHT[e2] = W_hh[g * 128 + k]; }
        }
    } else if (blk == 128) {
        float* WVRIH = ws + OFF_WVRIH;
        float* WVR1  = ws + OFF_WVR1;
        float* WVB   = ws + OFF_WVB;
        for (int g = tid; g < 384; g += 256) {
            float a = 0.f;
            for (int k = 0; k < 128; ++k) a = fmaf(v_r[k], W_ih[g * 256 + 128 + k], a);
            WVRIH[g] = a;
        }
        if (tid < 128) {
            float a = 0.f, b = 0.f;
            for (int k = 0; k < 128; ++k) {
                a = fmaf(v_r[k],    m2W1[(256 + k) * 128 + tid], a);
                b = fmaf(v_beta[k], m2W1[k * 128 + tid],         b);
            }
            WVR1[tid] = a; WVB[tid] = b;
        }
    } else if (blk < 145) {
        const int b = blk - 129;
        __shared__ int cs[Sq];
        for (int i = tid; i < Sq; i += 256) cs[i] = c_seq[b * Sq + i];
        __syncthreads();
        int* PO = (int*)(ws + OFF_PO) + b * Sq;
        for (int t = tid; t < Sq; t += 256) {
            int c = cs[t];
            int po = -1;
            for (int u = t - 1; u >= 0; --u) if (cs[u] == c) { po = u; break; }
            PO[t] = po;
        }
    } else if (blk < 161) {
        const int b = blk - 145;
        for (int s = tid; s < Sq; s += 256)
            gamma_out[b * Sq + s] = D1_w[d_seq[b * Sq + s]];
    }
}

// ============ K1: batched GEMM  [8192,128] x [128,512] -> xp | pre1 ============
__global__ __launch_bounds__(256) void k1_gemm(
    const int* __restrict__ d_seq, const float* __restrict__ D2_w,
    const float* __restrict__ m2W1, float* __restrict__ ws)
{
    __shared__ float As[64 * 128];   // [r][k]
    __shared__ float Bs[128 * 64];   // [k][c]
    const int blk = blockIdx.x, tid = threadIdx.x;
    const int nc = blk & 7;
    const int m0 = (blk >> 3) * 64;
    const float* WTIH = ws + OFF_WTIH;

    const float4* D2v = (const float4*)D2_w;
    for (int e = tid; e < 2048; e += 256) {
        int r = e >> 5, q = e & 31;
        int d = d_seq[m0 + r];
        *(float4*)&As[r * 128 + 4 * q] = D2v[d * 32 + q];
    }
    for (int e = tid; e < 2048; e += 256) {
        int k = e >> 4, q = e & 15;
        float4 v;
        if (nc < 6) v = *(const float4*)&WTIH[k * 384 + nc * 64 + 4 * q];
        else        v = *(const float4*)&m2W1[(128 + k) * 128 + (nc - 6) * 64 + 4 * q];
        *(float4*)&Bs[k * 64 + 4 * q] = v;
    }
    __syncthreads();

    const int tx = tid & 15, ty = tid >> 4;
    const int c0 = 4 * tx, r0 = 4 * ty;
    float acc[4][4];
#pragma unroll
    for (int i = 0; i < 4; ++i)
#pragma unroll
        for (int j = 0; j < 4; ++j) acc[i][j] = 0.f;

    for (int k = 0; k < 128; ++k) {
        float4 bv = *(const float4*)&Bs[k * 64 + c0];
#pragma unroll
        for (int i = 0; i < 4; ++i) {
            float a = As[(r0 + i) * 128 + k];
            acc[i][0] = fmaf(a, bv.x, acc[i][0]);
            acc[i][1] = fmaf(a, bv.y, acc[i][1]);
            acc[i][2] = fmaf(a, bv.z, acc[i][2]);
            acc[i][3] = fmaf(a, bv.w, acc[i][3]);
        }
    }
    float* XP   = ws + OFF_XP;
    float* PRE1 = ws + OFF_PRE1;
#pragma unroll
    for (int i = 0; i < 4; ++i) {
        int row = m0 + r0 + i;
        float4 v = make_float4(acc[i][0], acc[i][1], acc[i][2], acc[i][3]);
        if (nc < 6) *(float4*)&XP[row * 384 + nc * 64 + c0] = v;
        else        *(float4*)&PRE1[row * 128 + (nc - 6) * 64 + c0] = v;
    }
}

// ============ K2: GRU scan (blk 0..15) | beta scan (blk 16..31) ============
__global__ __launch_bounds__(384, 1) void k2_scan(
    const float* __restrict__ r_seq,
    const float* __restrict__ b_ih, const float* __restrict__ b_hh,
    const float* __restrict__ m2W2, const float* __restrict__ m2b1,
    const float* __restrict__ m2b2, const float* __restrict__ m2W3,
    const float* __restrict__ m2b3,
    float* __restrict__ ws,
    float* __restrict__ hseq_out, float* __restrict__ beta_out)
{
    __shared__ union {
        struct { float h[128]; float sum[256]; float xn[128]; float hn[128]; float r[512]; } g;
        struct { float bh[512]; float h1[128]; float red[2]; float r2[512]; int po_[512]; } bt;
    } sm;

    const int blk = blockIdx.x, tid = threadIdx.x;

    if (blk < 16) {
        // ---------------- GRU scan, batch b ----------------
        const int b = blk;
        const float* WHHT = ws + OFF_WHHT;
        float w[128];
#pragma unroll
        for (int k = 0; k < 128; ++k) w[k] = WHHT[k * 384 + tid];
        const float wvr = (ws + OFF_WVRIH)[tid];
        const float bih = b_ih[tid];
        const float bhh = b_hh[tid];
        for (int i = tid; i < Sq; i += 384) sm.g.r[i] = r_seq[b * Sq + i];
        if (tid < 128) sm.g.h[tid] = 0.f;
        __syncthreads();

        const float* xpb = ws + OFF_XP + (size_t)b * Sq * 384;
        float xp0 = xpb[tid];
        float xp1 = xpb[384 + tid];
        const float4* h4 = (const float4*)sm.g.h;

        for (int t = 0; t < Sq; ++t) {
            float xp2 = (t < Sq - 2) ? xpb[(t + 2) * 384 + tid] : 0.f;
            float x = xp0 + sm.g.r[t] * wvr + bih;
            float a0 = 0.f, a1 = 0.f, a2 = 0.f, a3 = 0.f;
#pragma unroll
            for (int kk = 0; kk < 32; ++kk) {
                float4 hv = h4[kk];
                a0 = fmaf(w[4 * kk + 0], hv.x, a0);
                a1 = fmaf(w[4 * kk + 1], hv.y, a1);
                a2 = fmaf(w[4 * kk + 2], hv.z, a2);
                a3 = fmaf(w[4 * kk + 3], hv.w, a3);
            }
            float hp = (a0 + a1) + (a2 + a3) + bhh;
            if (tid < 256) sm.g.sum[tid] = x + hp;
            else { sm.g.xn[tid - 256] = x; sm.g.hn[tid - 256] = hp; }
            __syncthreads();
            if (tid < 128) {
                float r = 1.f / (1.f + __expf(-sm.g.sum[tid]));
                float z = 1.f / (1.f + __expf(-sm.g.sum[128 + tid]));
                float npre = sm.g.xn[tid] + r * sm.g.hn[tid];
                float ax = fabsf(npre);
                float e2 = __expf(-2.f * ax);
                float n = copysignf((1.f - e2) / (1.f + e2), npre);
                float hnew = (1.f - z) * n + z * sm.g.h[tid];
                sm.g.h[tid] = hnew;
                hseq_out[(size_t)(b * Sq + t) * 128 + tid] = hnew;
            }
            __syncthreads();
            xp0 = xp1; xp1 = xp2;
        }
    } else {
        // ---------------- beta scan, batch b (2 barriers/step) ----------------
        const int b = blk - 16;
        float w2[128];
        float wvbj = 0.f, wvr1j = 0.f, b1j = 0.f, b2j = 0.f, w3j = 0.f;
        if (tid < 128) {
#pragma unroll
            for (int k = 0; k < 128; ++k) w2[k] = m2W2[k * 128 + tid];
            wvbj  = (ws + OFF_WVB)[tid];
            wvr1j = (ws + OFF_WVR1)[tid];
            b1j = m2b1[tid]; b2j = m2b2[tid]; w3j = m2W3[tid];
        }
        const float b3v = m2b3[0];
        const int* PO = (const int*)(ws + OFF_PO) + b * Sq;
        for (int i = tid; i < Sq; i += 384) {
            sm.bt.r2[i]  = r_seq[b * Sq + i];
            sm.bt.po_[i] = PO[i];
        }
        __syncthreads();

        const float* p1b = ws + OFF_PRE1 + (size_t)b * Sq * 128;
        float p1 = (tid < 128) ? p1b[tid] : 0.f;
        const float4* h14 = (const float4*)sm.bt.h1;
        float btap = 0.f;   // beta[t-1]

        for (int t = 0; t < Sq; ++t) {
            float p1n = (tid < 128 && t < Sq - 1) ? p1b[(t + 1) * 128 + tid] : 0.f;
            if (tid < 128) {
                int po = sm.bt.po_[t];
                float bp = (po == t - 1) ? btap : ((po >= 0) ? sm.bt.bh[po] : 0.f);
                sm.bt.h1[tid] = fmaxf(0.f, fmaf(bp, wvbj, fmaf(sm.bt.r2[t], wvr1j, p1 + b1j)));
            } else if (tid == 128 && t > 0) {
                sm.bt.bh[t - 1] = btap;
            }
            __syncthreads();
            if (tid < 128) {
                float a0 = 0.f, a1 = 0.f, a2 = 0.f, a3 = 0.f;
#pragma unroll
                for (int kk = 0; kk < 32; ++kk) {
                    float4 hv = h14[kk];
                    a0 = fmaf(w2[4 * kk + 0], hv.x, a0);
                    a1 = fmaf(w2[4 * kk + 1], hv.y, a1);
                    a2 = fmaf(w2[4 * kk + 2], hv.z, a2);
                    a3 = fmaf(w2[4 * kk + 3], hv.w, a3);
                }
                float h2 = fmaxf(0.f, (a0 + a1) + (a2 + a3) + b2j);
                float part = h2 * w3j;
#pragma unroll
                for (int off = 1; off < 64; off <<= 1) part += __shfl_xor(part, off);
                if ((tid & 63) == 0) sm.bt.red[tid >> 6] = part;
            }
            __syncthreads();
            float bta = sm.bt.red[0] + sm.bt.red[1] + b3v;
            if (tid == 192) beta_out[b * Sq + t] = bta;
            btap = bta;
            p1 = p1n;
        }
    }
}

// ============ K2b: dense C fill (zeros + latest-occurrence betas) ============
// grid = 16 b x 10 col-chunks(1024) x 4 t-quarters(128) = 640 blocks, 256 thr
__global__ __launch_bounds__(256) void k2b_fill(
    const int* __restrict__ c_seq, const float* __restrict__ beta_in,
    float* __restrict__ C_out)
{
    __shared__ int   scs[Sq];
    __shared__ float sbt[Sq];
    const int bid = blockIdx.x, tid = threadIdx.x;
    const int b = bid / 40, rem = bid % 40;
    const int chunk = rem >> 2, q = rem & 3;

    for (int i = tid; i < Sq; i += 256) {
        scs[i] = c_seq[b * Sq + i];
        sbt[i] = beta_in[b * Sq + i];
    }
    __syncthreads();

    const int c0 = chunk * 1024 + tid * 4;
    if (c0 >= NCq) return;

    float cur0 = 0.f, cur1 = 0.f, cur2 = 0.f, cur3 = 0.f;
    const int tlo = q * 128, thi = tlo + 128;
    float* base = C_out + (size_t)b * Sq * NCq + c0;

    for (int t = 0; t < tlo; ++t) {
        int ct = scs[t] - c0; float bv = sbt[t];
        cur0 = (ct == 0) ? bv : cur0;
        cur1 = (ct == 1) ? bv : cur1;
        cur2 = (ct == 2) ? bv : cur2;
        cur3 = (ct == 3) ? bv : cur3;
    }
    for (int t = tlo; t < thi; ++t) {
        int ct = scs[t] - c0; float bv = sbt[t];
        cur0 = (ct == 0) ? bv : cur0;
        cur1 = (ct == 1) ? bv : cur1;
        cur2 = (ct == 2) ? bv : cur2;
        cur3 = (ct == 3) ? bv : cur3;
        *(float4*)(base + (size_t)t * NCq) = make_float4(cur0, cur1, cur2, cur3);
    }
}

// ============ K3: alpha = mlp1(h_seq) ============
__global__ __launch_bounds__(256) void k3_alpha(
    const float* __restrict__ hseq,
    const float* __restrict__ W1, const float* __restrict__ b1,
    const float* __restrict__ W2, const float* __restrict__ b2,
    const float* __restrict__ W3, const float* __restrict__ b3,
    float* __restrict__ alpha_out)
{
    __shared__ float Hs[32 * 128];
    __shared__ float T1[32 * 128];
    __shared__ float red[4][16];
    const int blk = blockIdx.x, tid = threadIdx.x;
    const int row0 = blk * 32;

    for (int e = tid; e < 1024; e += 256) {
        int r = e >> 5, q = e & 31;
        *(float4*)&Hs[r * 128 + 4 * q] =
            *(const float4*)&hseq[(size_t)(row0 + r) * 128 + 4 * q];
    }
    __syncthreads();

    const int j = tid & 127, rh = tid >> 7;
    const float b1j = b1[j], b2j = b2[j], w3j = W3[j];
    float acc[16];
#pragma unroll
    for (int r = 0; r < 16; ++r) acc[r] = b1j;
    for (int k = 0; k < 128; ++k) {
        float w = W1[k * 128 + j];
#pragma unroll
        for (int r = 0; r < 16; ++r)
            acc[r] = fmaf(Hs[(rh * 16 + r) * 128 + k], w, acc[r]);
    }
#pragma unroll
    for (int r = 0; r < 16; ++r) {
        acc[r] = fmaxf(acc[r], 0.f);
        T1[(rh * 16 + r) * 128 + j] = acc[r];
    }
    __syncthreads();
    float acc2[16];
#pragma unroll
    for (int r = 0; r < 16; ++r) acc2[r] = b2j;
    for (int k = 0; k < 128; ++k) {
        float w = W2[k * 128 + j];
#pragma unroll
        for (int r = 0; r < 16; ++r)
            acc2[r] = fmaf(T1[(rh * 16 + r) * 128 + k], w, acc2[r]);
    }
#pragma unroll
    for (int r = 0; r < 16; ++r) {
        float p = fmaxf(acc2[r], 0.f) * w3j;
#pragma unroll
        for (int off = 1; off < 64; off <<= 1) p += __shfl_xor(p, off);
        if ((tid & 63) == 0) red[tid >> 6][r] = p;
    }
    __syncthreads();
    if (tid < 32) {
        int rr = tid & 15, g = tid >> 4;
        alpha_out[row0 + g * 16 + rr] = red[2 * g][rr] + red[2 * g + 1][rr] + b3[0];
    }
}

extern "C" void kernel_launch(void* const* d_in, const int* in_sizes, int n_in,
                              void* d_out, int out_size, void* d_ws, size_t ws_size,
                              hipStream_t stream) {
    const int*   c_seq = (const int*)d_in[0];
    const int*   d_seq = (const int*)d_in[1];
    const float* r_seq = (const float*)d_in[2];
    const float* D1_w  = (const float*)d_in[3];
    const float* D2_w  = (const float*)d_in[4];
    const float* v_r   = (const float*)d_in[5];
    const float* v_b   = (const float*)d_in[6];
    const float* W_ih  = (const float*)d_in[7];
    const float* W_hh  = (const float*)d_in[8];
    const float* b_ih  = (const float*)d_in[9];
    const float* b_hh  = (const float*)d_in[10];
    const float* m1W1  = (const float*)d_in[11];
    const float* m1b1  = (const float*)d_in[12];
    const float* m1W2  = (const float*)d_in[13];
    const float* m1b2  = (const float*)d_in[14];
    const float* m1W3  = (const float*)d_in[15];
    const float* m1b3  = (const float*)d_in[16];
    const float* m2W1  = (const float*)d_in[17];
    const float* m2b1  = (const float*)d_in[18];
    const float* m2W2  = (const float*)d_in[19];
    const float* m2b2  = (const float*)d_in[20];
    const float* m2W3  = (const float*)d_in[21];
    const float* m2b3  = (const float*)d_in[22];

    float* out   = (float*)d_out;
    float* alpha = out;                 // [16*512]
    float* beta  = out + 8192;          // [16*512]
    float* gamma = out + 16384;         // [16*512]
    float* hseq  = out + 24576;         // [16*512*128]
    float* Cseq  = out + 1073152;       // [16*512*10000]
    float* ws    = (float*)d_ws;

    hipLaunchKernelGGL(k0_prep, dim3(161), dim3(256), 0, stream,
                       c_seq, d_seq, D1_w, W_ih, W_hh, v_r, v_b, m2W1, ws, gamma);
    hipLaunchKernelGGL(k1_gemm, dim3(1024), dim3(256), 0, stream,
                       d_seq, D2_w, m2W1, ws);
    hipLaunchKernelGGL(k2_scan, dim3(32), dim3(384), 0, stream,
                       r_seq, b_ih, b_hh, m2W2, m2b1, m2b2, m2W3, m2b3,
                       ws, hseq, beta);
    hipLaunchKernelGGL(k2b_fill, dim3(640), dim3(256), 0, stream,
                       c_seq, beta, Cseq);
    hipLaunchKernelGGL(k3_alpha, dim3(256), dim3(256), 0, stream,
                       hseq, m1W1, m1b1, m1W2, m1b2, m1W3, m1b3, alpha);
}